// Round 6
// baseline (534.248 us; speedup 1.0000x reference)
//
#include <hip/hip_runtime.h>
#include <hip/hip_bf16.h>
#include <math.h>

#define NB 2
#define SEQ 1024
#define DM 768
#define NHEAD 12
#define HDIM 64
#define NEXP 8
#define FF 3072
#define NTOK (NB*SEQ)          // 2048
#define TDIM (3*DM)            // 2304
#define LNEPS 1e-5f
#define NSLOT (NTOK*2)         // 4096

typedef __attribute__((ext_vector_type(8))) short v8s;
typedef __attribute__((ext_vector_type(4))) float v4f;

// async global->LDS, 16B per lane; dst wave-uniform base (lane*16 added by HW)
#define GLDS16(src, dst) \
    __builtin_amdgcn_global_load_lds((const __attribute__((address_space(1))) unsigned int*)(src), \
                                     (__attribute__((address_space(3))) unsigned int*)(dst), 16, 0, 0)

// raw barrier with compiler memory fences on both sides (no vmcnt(0) drain!)
#define BARF() do { asm volatile("" ::: "memory"); __builtin_amdgcn_s_barrier(); asm volatile("" ::: "memory"); } while(0)
#define WAITV(n) asm volatile("s_waitcnt vmcnt(" #n ")" ::: "memory")

static __device__ __forceinline__ float bf2f(unsigned short u){
    return __uint_as_float(((unsigned)u) << 16);
}
static __device__ __forceinline__ unsigned short f2bf(float f){
    unsigned u = __float_as_uint(f);
    u += 0x7fffu + ((u >> 16) & 1u);   // RNE
    return (unsigned short)(u >> 16);
}
static __device__ __forceinline__ float gelu_exact(float x){
    return 0.5f * x * (1.0f + erff(x * 0.70710678118654752440f));
}

// ---------------- transpose+convert: in fp32 [R][C] -> out bf16 [C][R], per z slice ----------------
__global__ __launch_bounds__(256) void tconv_kernel(const float* __restrict__ in,
                                                    unsigned short* __restrict__ out,
                                                    int R, int C){
    __shared__ float T[32][33];
    size_t base = (size_t)blockIdx.z * R * C;
    int c0 = blockIdx.x * 32, r0 = blockIdx.y * 32;
    int t = threadIdx.x;
    int tr = t >> 3, tc4 = (t & 7) * 4;
    float4 v = *(const float4*)&in[base + (size_t)(r0 + tr) * C + c0 + tc4];
    T[tr][tc4+0] = v.x; T[tr][tc4+1] = v.y; T[tr][tc4+2] = v.z; T[tr][tc4+3] = v.w;
    __syncthreads();
    int oc = t >> 3, or4 = (t & 7) * 4;
    ushort4 o;
    o.x = f2bf(T[or4+0][oc]); o.y = f2bf(T[or4+1][oc]);
    o.z = f2bf(T[or4+2][oc]); o.w = f2bf(T[or4+3][oc]);
    *(ushort4*)&out[base + (size_t)(c0 + oc) * R + r0 + or4] = o;
}

// ---------------- LayerNorm (bf16 out only) ----------------
__global__ __launch_bounds__(256) void ln_b(const float* __restrict__ in,
                                            const float* __restrict__ g,
                                            const float* __restrict__ b,
                                            unsigned short* __restrict__ outb){
    int t = blockIdx.x;
    const float* row = in + (size_t)t * DM;
    int tid = threadIdx.x;
    float v0 = row[tid], v1 = row[tid + 256], v2 = row[tid + 512];
    float s  = v0 + v1 + v2;
    float ss = v0*v0 + v1*v1 + v2*v2;
    for (int off = 32; off; off >>= 1){
        s  += __shfl_down(s, off);
        ss += __shfl_down(ss, off);
    }
    __shared__ float ls[4], lss[4];
    int wid = tid >> 6, lane = tid & 63;
    if (lane == 0){ ls[wid] = s; lss[wid] = ss; }
    __syncthreads();
    if (tid == 0){
        float a = ls[0] + ls[1] + ls[2] + ls[3];
        float c = lss[0] + lss[1] + lss[2] + lss[3];
        float mu = a / (float)DM;
        float var = c / (float)DM - mu * mu;
        ls[0] = mu; lss[0] = rsqrtf(var + LNEPS);
    }
    __syncthreads();
    float mu = ls[0], rs = lss[0];
    unsigned short* obrow = outb + (size_t)t * DM;
    obrow[tid]     = f2bf((v0 - mu) * rs * g[tid]       + b[tid]);
    obrow[tid+256] = f2bf((v1 - mu) * rs * g[tid + 256] + b[tid + 256]);
    obrow[tid+512] = f2bf((v2 - mu) * rs * g[tid + 512] + b[tid + 512]);
}

// ---------------- LayerNorm + router fused: bf16 out + top-2 expert routing ----------------
__global__ __launch_bounds__(256) void ln_router(const float* __restrict__ in,
                                                 const float* __restrict__ g,
                                                 const float* __restrict__ b,
                                                 const float* __restrict__ wr,
                                                 unsigned short* __restrict__ outb,
                                                 int* __restrict__ cnt,
                                                 int* __restrict__ expTok,
                                                 int* __restrict__ tokE,
                                                 int* __restrict__ tokPos,
                                                 float* __restrict__ tokGate){
    int t = blockIdx.x;
    const float* row = in + (size_t)t * DM;
    int tid = threadIdx.x;
    float v0 = row[tid], v1 = row[tid + 256], v2 = row[tid + 512];
    float s  = v0 + v1 + v2;
    float ss = v0*v0 + v1*v1 + v2*v2;
    for (int off = 32; off; off >>= 1){
        s  += __shfl_down(s, off);
        ss += __shfl_down(ss, off);
    }
    __shared__ float ls[4], lss[4];
    __shared__ float wsum[4][NEXP];
    int wid = tid >> 6, lane = tid & 63;
    if (lane == 0){ ls[wid] = s; lss[wid] = ss; }
    __syncthreads();
    if (tid == 0){
        float a = ls[0] + ls[1] + ls[2] + ls[3];
        float c = lss[0] + lss[1] + lss[2] + lss[3];
        float mu = a / (float)DM;
        float var = c / (float)DM - mu * mu;
        ls[0] = mu; lss[0] = rsqrtf(var + LNEPS);
    }
    __syncthreads();
    float mu = ls[0], rs = lss[0];
    float o0 = (v0 - mu) * rs * g[tid]       + b[tid];
    float o1 = (v1 - mu) * rs * g[tid + 256] + b[tid + 256];
    float o2 = (v2 - mu) * rs * g[tid + 512] + b[tid + 512];
    unsigned short* obrow = outb + (size_t)t * DM;
    obrow[tid] = f2bf(o0); obrow[tid+256] = f2bf(o1); obrow[tid+512] = f2bf(o2);
    float p[NEXP];
    #pragma unroll
    for (int e = 0; e < NEXP; e++)
        p[e] = o0*wr[e*DM + tid] + o1*wr[e*DM + tid + 256] + o2*wr[e*DM + tid + 512];
    #pragma unroll
    for (int e = 0; e < NEXP; e++)
        for (int off = 32; off; off >>= 1) p[e] += __shfl_down(p[e], off);
    if (lane == 0){
        #pragma unroll
        for (int e = 0; e < NEXP; e++) wsum[wid][e] = p[e];
    }
    __syncthreads();
    if (tid == 0){
        float lg[NEXP];
        #pragma unroll
        for (int e = 0; e < NEXP; e++)
            lg[e] = wsum[0][e] + wsum[1][e] + wsum[2][e] + wsum[3][e];
        int i0 = 0; float m0 = lg[0];
        #pragma unroll
        for (int e = 1; e < NEXP; e++) if (lg[e] > m0){ m0 = lg[e]; i0 = e; }
        int i1 = -1; float m1 = -INFINITY;
        #pragma unroll
        for (int e = 0; e < NEXP; e++) if (e != i0 && lg[e] > m1){ m1 = lg[e]; i1 = e; }
        float mx = fmaxf(m0, m1);
        float e0 = __expf(m0 - mx), e1 = __expf(m1 - mx);
        float inv = 1.0f / (e0 + e1);
        int p0 = atomicAdd(&cnt[i0], 1);
        int p1 = atomicAdd(&cnt[i1], 1);
        expTok[i0*NTOK + p0] = t;
        expTok[i1*NTOK + p1] = t;
        tokE[t*2]   = i0; tokE[t*2+1]   = i1;
        tokPos[t*2] = p0; tokPos[t*2+1] = p1;
        tokGate[t*2]   = e0 * inv;
        tokGate[t*2+1] = e1 * inv;
    }
}

// ---------------- QKV GEMM (64x64 tile, depth-2) + fused attn prep epilogue ----------------
__global__ __launch_bounds__(256) void mm_qkv(const unsigned short* __restrict__ Ab,
                                              const unsigned short* __restrict__ Bb,
                                              const float* __restrict__ bias,
                                              unsigned short* __restrict__ Qb,
                                              unsigned short* __restrict__ Kb,
                                              unsigned short* __restrict__ Vt){
    __shared__ __align__(16) unsigned short As[2][64*32];
    __shared__ __align__(16) unsigned short Bs[2][64*32];
    int bm = blockIdx.y * 64, bn = blockIdx.x * 64;
    int tid = threadIdx.x, wave = tid >> 6, lane = tid & 63;
    int quad = lane >> 4, l15 = lane & 15;
    int wm = wave >> 1, wn = wave & 1;
    int arow = tid >> 2, achunk = (tid & 3) * 8;
    const unsigned short* aS = Ab + (size_t)(bm + arow) * DM + achunk;
    const unsigned short* bS = Bb + (size_t)(bn + arow) * DM + achunk;
    v4f acc[2][2];
    #pragma unroll
    for (int i = 0; i < 2; i++)
        #pragma unroll
        for (int j = 0; j < 2; j++) acc[i][j] = (v4f){0.f,0.f,0.f,0.f};

#define QKV_STAGE(buf, kt) do { int kb = (kt)*32; \
    GLDS16(aS + kb, &As[buf][(wave*16)*32]); \
    GLDS16(bS + kb, &Bs[buf][(wave*16)*32]); \
} while(0)
#define QKV_COMP(buf) do { \
    v8s a[2], bfr[2]; \
    _Pragma("unroll") \
    for (int i = 0; i < 2; i++){ \
        a[i]   = *(const v8s*)&As[buf][(wm*32 + i*16 + l15)*32 + quad*8]; \
        bfr[i] = *(const v8s*)&Bs[buf][(wn*32 + i*16 + l15)*32 + quad*8]; \
    } \
    _Pragma("unroll") \
    for (int mi = 0; mi < 2; mi++) \
        _Pragma("unroll") \
        for (int ni = 0; ni < 2; ni++) \
            acc[mi][ni] = __builtin_amdgcn_mfma_f32_16x16x32_bf16(a[mi], bfr[ni], acc[mi][ni], 0, 0, 0); \
} while(0)

    const int NK = DM/32;   // 24
    QKV_STAGE(0, 0);
    #pragma unroll 1
    for (int kt = 0; kt < NK; kt++){
        if (NK - kt > 1){ QKV_STAGE((kt+1)&1, kt+1); WAITV(2); }
        else            { WAITV(0); }
        BARF();
        QKV_COMP(kt&1);
        BARF();
    }
    int btyp = bn / DM;   // 0=Q, 1=K, 2=V (64 | 768)
    #pragma unroll
    for (int ni = 0; ni < 2; ni++){
        int n = bn + wn*32 + ni*16 + l15;
        float bb = bias[n];
        int hd = n % DM; int h = hd >> 6; int d = hd & 63;
        #pragma unroll
        for (int mi = 0; mi < 2; mi++){
            int m = bm + wm*32 + mi*16 + quad*4;
            int b = m >> 10, sd = m & 1023;
            size_t bhbase = (size_t)(b*NHEAD + h);
            if (btyp == 0){
                #pragma unroll
                for (int r = 0; r < 4; r++)
                    Qb[(bhbase*SEQ + sd + r)*HDIM + d] = f2bf((acc[mi][ni][r] + bb) * 0.125f);
            } else if (btyp == 1){
                #pragma unroll
                for (int r = 0; r < 4; r++)
                    Kb[(bhbase*SEQ + sd + r)*HDIM + d] = f2bf(acc[mi][ni][r] + bb);
            } else {
                ushort4 o;
                o.x = f2bf(acc[mi][ni][0] + bb); o.y = f2bf(acc[mi][ni][1] + bb);
                o.z = f2bf(acc[mi][ni][2] + bb); o.w = f2bf(acc[mi][ni][3] + bb);
                *(ushort4*)&Vt[(bhbase*HDIM + d)*SEQ + sd] = o;
            }
        }
    }
}

// ---------------- Flash attention: one wave per (bh, 32-query tile) ----------------
__global__ __launch_bounds__(64) void fattn(const unsigned short* __restrict__ Qb,
                                            const unsigned short* __restrict__ Kb,
                                            const unsigned short* __restrict__ Vt,
                                            unsigned short* __restrict__ ctxb){
    int bh = blockIdx.x >> 5;
    int q0 = (31 - (blockIdx.x & 31)) * 32;   // long tiles first
    int h = bh % NHEAD, b = bh / NHEAD;
    int lane = threadIdx.x;
    int quad = lane >> 4, l15 = lane & 15;

    __shared__ __align__(16) unsigned short Plds[32*32];

    const unsigned short* qp = Qb + ((size_t)bh*SEQ + q0 + l15) * HDIM + quad*8;
    v8s qa00 = *(const v8s*)qp;
    v8s qa01 = *(const v8s*)(qp + 32);
    v8s qa10 = *(const v8s*)(qp + 16*HDIM);
    v8s qa11 = *(const v8s*)(qp + 16*HDIM + 32);

    v4f o[2][4];
    #pragma unroll
    for (int i = 0; i < 2; i++)
        #pragma unroll
        for (int j = 0; j < 4; j++) o[i][j] = (v4f){0.f,0.f,0.f,0.f};
    float mrow[2][4], lrow[2][4];
    #pragma unroll
    for (int i = 0; i < 2; i++)
        #pragma unroll
        for (int r = 0; r < 4; r++){ mrow[i][r] = -1e30f; lrow[i][r] = 0.f; }

    int nch = (q0 >> 5) + 1;
    for (int ch = 0; ch < nch; ch++){
        int kt = ch * 32;
        const unsigned short* kp = Kb + ((size_t)bh*SEQ + kt + l15) * HDIM + quad*8;
        v8s k00 = *(const v8s*)kp;
        v8s k01 = *(const v8s*)(kp + 32);
        v8s k10 = *(const v8s*)(kp + 16*HDIM);
        v8s k11 = *(const v8s*)(kp + 16*HDIM + 32);
        v4f s00 = {0,0,0,0}, s01 = {0,0,0,0}, s10 = {0,0,0,0}, s11 = {0,0,0,0};
        s00 = __builtin_amdgcn_mfma_f32_16x16x32_bf16(qa00, k00, s00, 0, 0, 0);
        s00 = __builtin_amdgcn_mfma_f32_16x16x32_bf16(qa01, k01, s00, 0, 0, 0);
        s01 = __builtin_amdgcn_mfma_f32_16x16x32_bf16(qa00, k10, s01, 0, 0, 0);
        s01 = __builtin_amdgcn_mfma_f32_16x16x32_bf16(qa01, k11, s01, 0, 0, 0);
        s10 = __builtin_amdgcn_mfma_f32_16x16x32_bf16(qa10, k00, s10, 0, 0, 0);
        s10 = __builtin_amdgcn_mfma_f32_16x16x32_bf16(qa11, k01, s10, 0, 0, 0);
        s11 = __builtin_amdgcn_mfma_f32_16x16x32_bf16(qa10, k10, s11, 0, 0, 0);
        s11 = __builtin_amdgcn_mfma_f32_16x16x32_bf16(qa11, k11, s11, 0, 0, 0);

        int key0 = kt + l15, key1 = kt + 16 + l15;
        float alpha[2][4];
        #pragma unroll
        for (int mi = 0; mi < 2; mi++){
            #pragma unroll
            for (int r = 0; r < 4; r++){
                int qrow = q0 + mi*16 + quad*4 + r;
                float sv0 = mi ? s10[r] : s00[r];
                float sv1 = mi ? s11[r] : s01[r];
                float v0 = (key0 <= qrow) ? sv0 : -1e30f;
                float v1 = (key1 <= qrow) ? sv1 : -1e30f;
                float mx = fmaxf(v0, v1);
                mx = fmaxf(mx, __shfl_xor(mx, 1));
                mx = fmaxf(mx, __shfl_xor(mx, 2));
                mx = fmaxf(mx, __shfl_xor(mx, 4));
                mx = fmaxf(mx, __shfl_xor(mx, 8));
                float mn = fmaxf(mrow[mi][r], mx);
                alpha[mi][r] = __expf(mrow[mi][r] - mn);
                float p0 = __expf(v0 - mn);
                float p1 = __expf(v1 - mn);
                float ps = p0 + p1;
                ps += __shfl_xor(ps, 1);
                ps += __shfl_xor(ps, 2);
                ps += __shfl_xor(ps, 4);
                ps += __shfl_xor(ps, 8);
                lrow[mi][r] = lrow[mi][r] * alpha[mi][r] + ps;
                mrow[mi][r] = mn;
                Plds[(mi*16 + quad*4 + r)*32 + l15]      = f2bf(p0);
                Plds[(mi*16 + quad*4 + r)*32 + 16 + l15] = f2bf(p1);
            }
        }
        #pragma unroll
        for (int mi = 0; mi < 2; mi++)
            #pragma unroll
            for (int df = 0; df < 4; df++)
                #pragma unroll
                for (int r = 0; r < 4; r++)
                    o[mi][df][r] *= alpha[mi][r];
        __syncthreads();
        v8s pa0 = *(const v8s*)&Plds[l15*32 + quad*8];
        v8s pa1 = *(const v8s*)&Plds[(16 + l15)*32 + quad*8];
        const unsigned short* vp = Vt + ((size_t)bh*HDIM + l15) * SEQ + kt + quad*8;
        #pragma unroll
        for (int df = 0; df < 4; df++){
            v8s vb = *(const v8s*)(vp + df*16*SEQ);
            o[0][df] = __builtin_amdgcn_mfma_f32_16x16x32_bf16(pa0, vb, o[0][df], 0, 0, 0);
            o[1][df] = __builtin_amdgcn_mfma_f32_16x16x32_bf16(pa1, vb, o[1][df], 0, 0, 0);
        }
        __syncthreads();
    }
    #pragma unroll
    for (int mi = 0; mi < 2; mi++){
        #pragma unroll
        for (int r = 0; r < 4; r++){
            float inv = 1.0f / lrow[mi][r];
            size_t orow = (size_t)(b*SEQ + q0 + mi*16 + quad*4 + r) * DM + h*HDIM;
            #pragma unroll
            for (int df = 0; df < 4; df++)
                ctxb[orow + df*16 + l15] = f2bf(o[mi][df][r] * inv);
        }
    }
}

// ---------------- attn-proj GEMM (64x64 tile, depth-3 prefetch) + bias + residual -> hs fp32 ----------------
__global__ __launch_bounds__(256) void mm_attnproj(const unsigned short* __restrict__ Ab,
                                                   const unsigned short* __restrict__ Bb,
                                                   const float* __restrict__ bias,
                                                   const float* __restrict__ res,
                                                   float* __restrict__ C){
    __shared__ __align__(16) unsigned short As[4][64*32];
    __shared__ __align__(16) unsigned short Bs[4][64*32];
    int bm = blockIdx.y * 64, bn = blockIdx.x * 64;
    int tid = threadIdx.x, wave = tid >> 6, lane = tid & 63;
    int quad = lane >> 4, l15 = lane & 15;
    int wm = wave >> 1, wn = wave & 1;
    int lrow = lane >> 2, lchunk = (lane & 3) * 8;
    const unsigned short* aS = Ab + (size_t)(bm + wave*16 + lrow) * DM + lchunk;
    const unsigned short* bS = Bb + (size_t)(bn + wave*16 + lrow) * DM + lchunk;
    v4f acc[2][2];
    #pragma unroll
    for (int i = 0; i < 2; i++)
        #pragma unroll
        for (int j = 0; j < 2; j++) acc[i][j] = (v4f){0.f,0.f,0.f,0.f};

#define AP_STAGE(buf, kt) do { int kb = (kt)*32; \
    GLDS16(aS + kb, &As[buf][(wave*16)*32]); \
    GLDS16(bS + kb, &Bs[buf][(wave*16)*32]); \
} while(0)
#define AP_COMP(buf) do { \
    v8s a[2], bfr[2]; \
    _Pragma("unroll") \
    for (int i = 0; i < 2; i++){ \
        a[i]   = *(const v8s*)&As[buf][(wm*32 + i*16 + l15)*32 + quad*8]; \
        bfr[i] = *(const v8s*)&Bs[buf][(wn*32 + i*16 + l15)*32 + quad*8]; \
    } \
    _Pragma("unroll") \
    for (int mi = 0; mi < 2; mi++) \
        _Pragma("unroll") \
        for (int ni = 0; ni < 2; ni++) \
            acc[mi][ni] = __builtin_amdgcn_mfma_f32_16x16x32_bf16(a[mi], bfr[ni], acc[mi][ni], 0, 0, 0); \
} while(0)

    const int NK = DM/32;   // 24
    AP_STAGE(0, 0); AP_STAGE(1, 1); AP_STAGE(2, 2);
    #pragma unroll 1
    for (int kt = 0; kt < NK; kt++){
        int rem = NK - kt;
        if (rem > 3){ AP_STAGE((kt+3)&3, kt+3); WAITV(6); }
        else if (rem == 3){ WAITV(4); }
        else if (rem == 2){ WAITV(2); }
        else { WAITV(0); }
        BARF();
        AP_COMP(kt&3);
        BARF();
    }
    #pragma unroll
    for (int ni = 0; ni < 2; ni++){
        int n = bn + wn*32 + ni*16 + l15;
        float bb = bias[n];
        #pragma unroll
        for (int mi = 0; mi < 2; mi++){
            int m = bm + wm*32 + mi*16 + quad*4;
            #pragma unroll
            for (int r = 0; r < 4; r++)
                C[(size_t)(m + r) * DM + n] = acc[mi][ni][r] + bb + res[(size_t)(m + r) * DM + n];
        }
    }
}

// ---------------- MoE fc: 256x256 tile, BK=64, 8 waves, 2-phase counted-vmcnt, XOR-swizzled LDS ----------------
// grid 1D: bid = e + 8*(mt + 8*nt); expert in low 3 bits -> XCD pinning
__global__ __launch_bounds__(512, 2) void mm_fc(const unsigned short* __restrict__ Xb,
                                                const unsigned short* __restrict__ Wb,
                                                const float* __restrict__ bfc,
                                                const int* __restrict__ expTok,
                                                const int* __restrict__ cnt,
                                                const int* __restrict__ offE,
                                                unsigned short* __restrict__ H){
    int bid = blockIdx.x;
    int e = bid & 7;
    int t2 = bid >> 3;
    int mt = t2 & 7;
    int bn = (t2 >> 3) * 256;
    int c = cnt[e];
    int rows = c - mt * 256;
    if (rows <= 0) return;
    __shared__ __align__(16) unsigned short As[2][256*64];   // 64 KB
    __shared__ __align__(16) unsigned short Bs[2][256*64];   // 64 KB
    int tid = threadIdx.x, wave = tid >> 6, lane = tid & 63;
    int quad = lane >> 4, l15 = lane & 15;
    int wm = wave >> 2, wn = wave & 3;      // 2M x 4N waves, wave tile 128x64
    // staging: each wave stages 32 A-rows + 32 B-rows as 4 stripes of 8 rows.
    // gload_lds dest is linear; global source chunk is pre-permuted: chunk' = chunk ^ (row&7)
    int srow = lane >> 3;                   // row within 8-row stripe
    int schunk = (lane & 7) ^ srow;         // inverse-swizzled source chunk
    const unsigned short* Be = Wb + (size_t)e * FF * DM;
    const unsigned short* aSrc[4];
    const unsigned short* bSrc[4];
    #pragma unroll
    for (int s = 0; s < 4; s++){
        int arow = mt*256 + wave*32 + s*8 + srow;
        if (arow >= c) arow = c - 1;
        int tok = expTok[e*NTOK + arow];
        aSrc[s] = Xb + (size_t)tok * DM + schunk*8;
        bSrc[s] = Be + (size_t)(bn + wave*32 + s*8 + srow) * DM + schunk*8;
    }
    v4f acc[8][4];
    #pragma unroll
    for (int i = 0; i < 8; i++)
        #pragma unroll
        for (int j = 0; j < 4; j++) acc[i][j] = (v4f){0.f,0.f,0.f,0.f};

#define FC_STG(buf, kt) do { int kb = (kt)*64; \
    _Pragma("unroll") \
    for (int s = 0; s < 4; s++){ \
        GLDS16(aSrc[s] + kb, &As[buf][(wave*32 + s*8)*64]); \
        GLDS16(bSrc[s] + kb, &Bs[buf][(wave*32 + s*8)*64]); \
    } \
} while(0)
#define FC_CMP(buf) do { \
    _Pragma("unroll") \
    for (int h = 0; h < 2; h++){ \
        v8s a[8], bq[4]; \
        _Pragma("unroll") \
        for (int mi = 0; mi < 8; mi++) \
            a[mi] = *(const v8s*)&As[buf][(wm*128 + mi*16 + l15)*64 + ((h*4 + quad) ^ (l15 & 7))*8]; \
        _Pragma("unroll") \
        for (int ni = 0; ni < 4; ni++) \
            bq[ni] = *(const v8s*)&Bs[buf][(wn*64 + ni*16 + l15)*64 + ((h*4 + quad) ^ (l15 & 7))*8]; \
        _Pragma("unroll") \
        for (int mi = 0; mi < 8; mi++) \
            _Pragma("unroll") \
            for (int ni = 0; ni < 4; ni++) \
                acc[mi][ni] = __builtin_amdgcn_mfma_f32_16x16x32_bf16(a[mi], bq[ni], acc[mi][ni], 0, 0, 0); \
    } \
} while(0)

    const int NK = DM/64;   // 12
    FC_STG(0, 0);
    #pragma unroll 1
    for (int kt = 0; kt < NK; kt++){
        if (kt + 1 < NK){ FC_STG((kt+1)&1, kt+1); WAITV(8); }
        else            { WAITV(0); }
        BARF();
        FC_CMP(kt&1);
        BARF();
    }
    int slot0 = offE[e] + mt*256;
    #pragma unroll
    for (int ni = 0; ni < 4; ni++){
        int n = bn + wn*64 + ni*16 + l15;
        float bb = bfc[(size_t)e * FF + n];
        #pragma unroll
        for (int mi = 0; mi < 8; mi++){
            int ml = wm*128 + mi*16 + quad*4;
            #pragma unroll
            for (int r = 0; r < 4; r++)
                if (ml + r < rows)
                    H[(size_t)(slot0 + ml + r) * FF + n] = f2bf(gelu_exact(acc[mi][ni][r] + bb));
        }
    }
}

// ---------------- MoE proj: 256x128 tile, BK=64, split-K=2, 8 waves, 2-phase counted-vmcnt ----------------
// grid 1D: bid = e + 8*(mt + 8*(sk + 2*nt))
__global__ __launch_bounds__(512, 2) void mm_proj(const unsigned short* __restrict__ H,
                                                  const unsigned short* __restrict__ Wb,
                                                  const int* __restrict__ cnt,
                                                  const int* __restrict__ offE,
                                                  float* __restrict__ Yp){
    int bid = blockIdx.x;
    int e = bid & 7;
    int t2 = bid >> 3;
    int mt = t2 & 7;
    int t3 = t2 >> 3;
    int sk = t3 & 1;
    int bn = (t3 >> 1) * 128;
    int c = cnt[e];
    int rows = c - mt * 256;
    if (rows <= 0) return;
    __shared__ __align__(16) unsigned short As[2][256*64];   // 64 KB
    __shared__ __align__(16) unsigned short Bs[2][128*64];   // 32 KB
    int tid = threadIdx.x, wave = tid >> 6, lane = tid & 63;
    int quad = lane >> 4, l15 = lane & 15;
    int wm = wave >> 1, wn = wave & 1;      // 4M x 2N waves, wave tile 64x64
    int slot0 = offE[e] + mt*256;
    int srow = lane >> 3;
    int schunk = (lane & 7) ^ srow;
    const unsigned short* Be = Wb + (size_t)e * DM * FF;
    const unsigned short* aSrc[4];
    const unsigned short* bSrc[2];
    #pragma unroll
    for (int s = 0; s < 4; s++){
        int arow = wave*32 + s*8 + srow;
        if (arow >= rows) arow = rows - 1;
        aSrc[s] = H + (size_t)(slot0 + arow) * FF + sk*1536 + schunk*8;
    }
    #pragma unroll
    for (int s = 0; s < 2; s++)
        bSrc[s] = Be + (size_t)(bn + wave*16 + s*8 + srow) * FF + sk*1536 + schunk*8;
    v4f acc[4][4];
    #pragma unroll
    for (int i = 0; i < 4; i++)
        #pragma unroll
        for (int j = 0; j < 4; j++) acc[i][j] = (v4f){0.f,0.f,0.f,0.f};

#define PJ_STG(buf, kt) do { int kb = (kt)*64; \
    _Pragma("unroll") \
    for (int s = 0; s < 4; s++) \
        GLDS16(aSrc[s] + kb, &As[buf][(wave*32 + s*8)*64]); \
    _Pragma("unroll") \
    for (int s = 0; s < 2; s++) \
        GLDS16(bSrc[s] + kb, &Bs[buf][(wave*16 + s*8)*64]); \
} while(0)
#define PJ_CMP(buf) do { \
    _Pragma("unroll") \
    for (int h = 0; h < 2; h++){ \
        v8s a[4], bq[4]; \
        _Pragma("unroll") \
        for (int mi = 0; mi < 4; mi++) \
            a[mi] = *(const v8s*)&As[buf][(wm*64 + mi*16 + l15)*64 + ((h*4 + quad) ^ (l15 & 7))*8]; \
        _Pragma("unroll") \
        for (int ni = 0; ni < 4; ni++) \
            bq[ni] = *(const v8s*)&Bs[buf][(wn*64 + ni*16 + l15)*64 + ((h*4 + quad) ^ (l15 & 7))*8]; \
        _Pragma("unroll") \
        for (int mi = 0; mi < 4; mi++) \
            _Pragma("unroll") \
            for (int ni = 0; ni < 4; ni++) \
                acc[mi][ni] = __builtin_amdgcn_mfma_f32_16x16x32_bf16(a[mi], bq[ni], acc[mi][ni], 0, 0, 0); \
    } \
} while(0)

    const int NK = 1536/64;   // 24
    PJ_STG(0, 0);
    #pragma unroll 1
    for (int kt = 0; kt < NK; kt++){
        if (kt + 1 < NK){ PJ_STG((kt+1)&1, kt+1); WAITV(6); }
        else            { WAITV(0); }
        BARF();
        PJ_CMP(kt&1);
        BARF();
    }
    float* Yo = Yp + (size_t)sk * NSLOT * DM;
    #pragma unroll
    for (int ni = 0; ni < 4; ni++){
        int n = bn + wn*64 + ni*16 + l15;
        #pragma unroll
        for (int mi = 0; mi < 4; mi++){
            int ml = wm*64 + mi*16 + quad*4;
            #pragma unroll
            for (int r = 0; r < 4; r++)
                if (ml + r < rows)
                    Yo[(size_t)(slot0 + ml + r) * DM + n] = acc[mi][ni][r];
        }
    }
}

__global__ void offsets_kernel(const int* __restrict__ cnt, int* __restrict__ offE){
    if (threadIdx.x == 0 && blockIdx.x == 0){
        int a = 0;
        for (int e = 0; e < NEXP; e++){ offE[e] = a; a += cnt[e]; }
    }
}

// ---------------- Combine: out = hs + sum_k gate_k * (Yp0+Yp1 + b_proj[e_k]) ----------------
__global__ __launch_bounds__(256) void combine_kernel(const float* __restrict__ hs,
                                                      const float* __restrict__ Yp,
                                                      const float* __restrict__ bproj,
                                                      const int* __restrict__ tokE,
                                                      const int* __restrict__ tokPos,
                                                      const float* __restrict__ tokGate,
                                                      const int* __restrict__ offE,
                                                      float* __restrict__ out){
    int t = blockIdx.x;
    int e0 = tokE[t*2], e1 = tokE[t*2+1];
    int s0 = offE[e0] + tokPos[t*2];
    int s1 = offE[e1] + tokPos[t*2+1];
    float g0 = tokGate[t*2], g1 = tokGate[t*2+1];
    const float* y0a = Yp + (size_t)s0 * DM;
    const float* y0b = Yp + (size_t)NSLOT * DM + (size_t)s0 * DM;
    const float* y1a = Yp + (size_t)s1 * DM;
    const float* y1b = Yp + (size_t)NSLOT * DM + (size_t)s1 * DM;
    const float* b0 = bproj + (size_t)e0 * DM;
    const float* b1 = bproj + (size_t)e1 * DM;
    const float* hr = hs + (size_t)t * DM;
    float* orow = out + (size_t)t * DM;
    for (int d = threadIdx.x; d < DM; d += 256){
        orow[d] = hr[d] + g0 * (y0a[d] + y0b[d] + b0[d]) + g1 * (y1a[d] + y1b[d] + b1[d]);
    }
}

extern "C" void kernel_launch(void* const* d_in, const int* in_sizes, int n_in,
                              void* d_out, int out_size, void* d_ws, size_t ws_size,
                              hipStream_t stream){
    (void)in_sizes; (void)n_in; (void)out_size; (void)ws_size;
    const float* hidden  = (const float*)d_in[0];
    const float* ln1_g   = (const float*)d_in[1];
    const float* ln1_b   = (const float*)d_in[2];
    const float* w_attn  = (const float*)d_in[3];
    const float* b_attn  = (const float*)d_in[4];
    const float* w_aproj = (const float*)d_in[5];
    const float* b_aproj = (const float*)d_in[6];
    const float* ln2_g   = (const float*)d_in[7];
    const float* ln2_b   = (const float*)d_in[8];
    const float* w_rout  = (const float*)d_in[9];
    const float* w_fc    = (const float*)d_in[10];
    const float* b_fc    = (const float*)d_in[11];
    const float* w_proj  = (const float*)d_in[12];
    const float* b_proj  = (const float*)d_in[13];
    float* out = (float*)d_out;

    char* ws = (char*)d_ws;
    // layout (bytes):
    float*          hs   = (float*)(ws + 0);                      //  6,291,456
    unsigned short* xb   = (unsigned short*)(ws + 6291456);       //  3,145,728
    unsigned short* Qb   = (unsigned short*)(ws + 9437184);       //  3,145,728
    unsigned short* Kb   = (unsigned short*)(ws + 12582912);      //  3,145,728
    unsigned short* Vt   = (unsigned short*)(ws + 15728640);      //  3,145,728
    unsigned short* ctxb = (unsigned short*)(ws + 18874368);      //  3,145,728
    unsigned short* Wab  = (unsigned short*)(ws + 22020096);      //  3,538,944
    unsigned short* Wapb = (unsigned short*)(ws + 25559040);      //  1,179,648
    // H overlays Qb..Wapb (all dead by mm_fc) + fresh space up to 34,603,008
    unsigned short* H    = (unsigned short*)(ws + 9437184);       // 25,165,824 overlay
    unsigned short* Wfcb = (unsigned short*)(ws + 34603008);      // 37,748,736
    unsigned short* Wprb = (unsigned short*)(ws + 72351744);      // 37,748,736
    // Yp (2 split-K partials) overlays Wfcb (dead after mm_fc)
    float*          Yp   = (float*)(ws + 34603008);               // 25,165,824 overlay
    char* rt = ws + 110100480;
    int* cnt      = (int*)(rt + 0);
    int* offE     = (int*)(rt + 64);
    int* expTok   = (int*)(rt + 128);                   // 65,536
    int* tokE     = (int*)(rt + 128 + 65536);           // 16,384
    int* tokPos   = (int*)(rt + 128 + 81920);           // 16,384
    float* tokGate= (float*)(rt + 128 + 98304);         // 16,384

    hipMemsetAsync(cnt, 0, NEXP * sizeof(int), stream);

    // weight transpose+convert to bf16 [N][K]
    tconv_kernel<<<dim3(TDIM/32, DM/32, 1), 256, 0, stream>>>(w_attn, Wab, DM, TDIM);
    tconv_kernel<<<dim3(DM/32, DM/32, 1), 256, 0, stream>>>(w_aproj, Wapb, DM, DM);
    tconv_kernel<<<dim3(FF/32, DM/32, NEXP), 256, 0, stream>>>(w_fc, Wfcb, DM, FF);
    tconv_kernel<<<dim3(DM/32, FF/32, NEXP), 256, 0, stream>>>(w_proj, Wprb, FF, DM);

    ln_b<<<NTOK, 256, 0, stream>>>(hidden, ln1_g, ln1_b, xb);
    mm_qkv<<<dim3(TDIM/64, NTOK/64), 256, 0, stream>>>(xb, Wab, b_attn, Qb, Kb, Vt);
    fattn<<<NB*NHEAD*32, 64, 0, stream>>>(Qb, Kb, Vt, ctxb);
    mm_attnproj<<<dim3(DM/64, NTOK/64), 256, 0, stream>>>(ctxb, Wapb, b_aproj, hidden, hs);
    ln_router<<<NTOK, 256, 0, stream>>>(hs, ln2_g, ln2_b, w_rout, xb,
                                        cnt, expTok, tokE, tokPos, tokGate);
    offsets_kernel<<<1, 64, 0, stream>>>(cnt, offE);
    // 1D grids, expert in low 3 bits -> XCD pinning; 256-row m-tiles (max 8/expert)
    mm_fc<<<8 * 8 * (FF/256), 512, 0, stream>>>(xb, Wfcb, b_fc, expTok, cnt, offE, H);
    mm_proj<<<8 * 8 * 2 * (DM/128), 512, 0, stream>>>(H, Wprb, cnt, offE, Yp);
    combine_kernel<<<NTOK, 256, 0, stream>>>(hs, Yp, b_proj, tokE, tokPos, tokGate, offE, out);
}

// Round 7
// 480.016 us; speedup vs baseline: 1.1130x; 1.1130x over previous
//
#include <hip/hip_runtime.h>
#include <hip/hip_bf16.h>
#include <math.h>

#define NB 2
#define SEQ 1024
#define DM 768
#define NHEAD 12
#define HDIM 64
#define NEXP 8
#define FF 3072
#define NTOK (NB*SEQ)          // 2048
#define TDIM (3*DM)            // 2304
#define LNEPS 1e-5f
#define NSLOT (NTOK*2)         // 4096

typedef __attribute__((ext_vector_type(8))) short v8s;
typedef __attribute__((ext_vector_type(4))) float v4f;

// async global->LDS, 16B per lane; dst wave-uniform base (lane*16 added by HW)
#define GLDS16(src, dst) \
    __builtin_amdgcn_global_load_lds((const __attribute__((address_space(1))) unsigned int*)(src), \
                                     (__attribute__((address_space(3))) unsigned int*)(dst), 16, 0, 0)

// raw barrier with compiler memory fences on both sides (no vmcnt(0) drain!)
#define BARF() do { asm volatile("" ::: "memory"); __builtin_amdgcn_s_barrier(); asm volatile("" ::: "memory"); } while(0)
#define WAITV(n) asm volatile("s_waitcnt vmcnt(" #n ")" ::: "memory")

static __device__ __forceinline__ float bf2f(unsigned short u){
    return __uint_as_float(((unsigned)u) << 16);
}
static __device__ __forceinline__ unsigned short f2bf(float f){
    unsigned u = __float_as_uint(f);
    u += 0x7fffu + ((u >> 16) & 1u);   // RNE
    return (unsigned short)(u >> 16);
}
static __device__ __forceinline__ float gelu_exact(float x){
    return 0.5f * x * (1.0f + erff(x * 0.70710678118654752440f));
}

// ---------------- transpose+convert v2: in fp32 [R][C] -> out bf16 [C][R], per z slice ----------------
// 64 R-rows x 32 C-cols per block; 16B output stores
__global__ __launch_bounds__(256) void tconv_kernel(const float* __restrict__ in,
                                                    unsigned short* __restrict__ out,
                                                    int R, int C){
    __shared__ float T[64][33];
    size_t base = (size_t)blockIdx.z * R * C;
    int c0 = blockIdx.x * 32, r0 = blockIdx.y * 64;
    int t = threadIdx.x;
    int row = t >> 2, cq = (t & 3) * 8;
    const float* ip = &in[base + (size_t)(r0 + row) * C + c0 + cq];
    float4 va = *(const float4*)ip;
    float4 vb = *(const float4*)(ip + 4);
    T[row][cq+0]=va.x; T[row][cq+1]=va.y; T[row][cq+2]=va.z; T[row][cq+3]=va.w;
    T[row][cq+4]=vb.x; T[row][cq+5]=vb.y; T[row][cq+6]=vb.z; T[row][cq+7]=vb.w;
    __syncthreads();
    int oc = t >> 3, or8 = (t & 7) * 8;
    unsigned short ov[8];
    #pragma unroll
    for (int i = 0; i < 8; i++) ov[i] = f2bf(T[or8 + i][oc]);
    *(v8s*)&out[base + (size_t)(c0 + oc) * R + r0 + or8] = *(const v8s*)ov;
}

// ---------------- LayerNorm (bf16 out only) ----------------
__global__ __launch_bounds__(256) void ln_b(const float* __restrict__ in,
                                            const float* __restrict__ g,
                                            const float* __restrict__ b,
                                            unsigned short* __restrict__ outb){
    int t = blockIdx.x;
    const float* row = in + (size_t)t * DM;
    int tid = threadIdx.x;
    float v0 = row[tid], v1 = row[tid + 256], v2 = row[tid + 512];
    float s  = v0 + v1 + v2;
    float ss = v0*v0 + v1*v1 + v2*v2;
    for (int off = 32; off; off >>= 1){
        s  += __shfl_down(s, off);
        ss += __shfl_down(ss, off);
    }
    __shared__ float ls[4], lss[4];
    int wid = tid >> 6, lane = tid & 63;
    if (lane == 0){ ls[wid] = s; lss[wid] = ss; }
    __syncthreads();
    if (tid == 0){
        float a = ls[0] + ls[1] + ls[2] + ls[3];
        float c = lss[0] + lss[1] + lss[2] + lss[3];
        float mu = a / (float)DM;
        float var = c / (float)DM - mu * mu;
        ls[0] = mu; lss[0] = rsqrtf(var + LNEPS);
    }
    __syncthreads();
    float mu = ls[0], rs = lss[0];
    unsigned short* obrow = outb + (size_t)t * DM;
    obrow[tid]     = f2bf((v0 - mu) * rs * g[tid]       + b[tid]);
    obrow[tid+256] = f2bf((v1 - mu) * rs * g[tid + 256] + b[tid + 256]);
    obrow[tid+512] = f2bf((v2 - mu) * rs * g[tid + 512] + b[tid + 512]);
}

// ---------------- LayerNorm + router fused: bf16 out + top-2 expert routing ----------------
__global__ __launch_bounds__(256) void ln_router(const float* __restrict__ in,
                                                 const float* __restrict__ g,
                                                 const float* __restrict__ b,
                                                 const float* __restrict__ wr,
                                                 unsigned short* __restrict__ outb,
                                                 int* __restrict__ cnt,
                                                 int* __restrict__ expTok,
                                                 int* __restrict__ tokE,
                                                 int* __restrict__ tokPos,
                                                 float* __restrict__ tokGate){
    int t = blockIdx.x;
    const float* row = in + (size_t)t * DM;
    int tid = threadIdx.x;
    float v0 = row[tid], v1 = row[tid + 256], v2 = row[tid + 512];
    float s  = v0 + v1 + v2;
    float ss = v0*v0 + v1*v1 + v2*v2;
    for (int off = 32; off; off >>= 1){
        s  += __shfl_down(s, off);
        ss += __shfl_down(ss, off);
    }
    __shared__ float ls[4], lss[4];
    __shared__ float wsum[4][NEXP];
    int wid = tid >> 6, lane = tid & 63;
    if (lane == 0){ ls[wid] = s; lss[wid] = ss; }
    __syncthreads();
    if (tid == 0){
        float a = ls[0] + ls[1] + ls[2] + ls[3];
        float c = lss[0] + lss[1] + lss[2] + lss[3];
        float mu = a / (float)DM;
        float var = c / (float)DM - mu * mu;
        ls[0] = mu; lss[0] = rsqrtf(var + LNEPS);
    }
    __syncthreads();
    float mu = ls[0], rs = lss[0];
    float o0 = (v0 - mu) * rs * g[tid]       + b[tid];
    float o1 = (v1 - mu) * rs * g[tid + 256] + b[tid + 256];
    float o2 = (v2 - mu) * rs * g[tid + 512] + b[tid + 512];
    unsigned short* obrow = outb + (size_t)t * DM;
    obrow[tid] = f2bf(o0); obrow[tid+256] = f2bf(o1); obrow[tid+512] = f2bf(o2);
    float p[NEXP];
    #pragma unroll
    for (int e = 0; e < NEXP; e++)
        p[e] = o0*wr[e*DM + tid] + o1*wr[e*DM + tid + 256] + o2*wr[e*DM + tid + 512];
    #pragma unroll
    for (int e = 0; e < NEXP; e++)
        for (int off = 32; off; off >>= 1) p[e] += __shfl_down(p[e], off);
    if (lane == 0){
        #pragma unroll
        for (int e = 0; e < NEXP; e++) wsum[wid][e] = p[e];
    }
    __syncthreads();
    if (tid == 0){
        float lg[NEXP];
        #pragma unroll
        for (int e = 0; e < NEXP; e++)
            lg[e] = wsum[0][e] + wsum[1][e] + wsum[2][e] + wsum[3][e];
        int i0 = 0; float m0 = lg[0];
        #pragma unroll
        for (int e = 1; e < NEXP; e++) if (lg[e] > m0){ m0 = lg[e]; i0 = e; }
        int i1 = -1; float m1 = -INFINITY;
        #pragma unroll
        for (int e = 0; e < NEXP; e++) if (e != i0 && lg[e] > m1){ m1 = lg[e]; i1 = e; }
        float mx = fmaxf(m0, m1);
        float e0 = __expf(m0 - mx), e1 = __expf(m1 - mx);
        float inv = 1.0f / (e0 + e1);
        int p0 = atomicAdd(&cnt[i0], 1);
        int p1 = atomicAdd(&cnt[i1], 1);
        expTok[i0*NTOK + p0] = t;
        expTok[i1*NTOK + p1] = t;
        tokE[t*2]   = i0; tokE[t*2+1]   = i1;
        tokPos[t*2] = p0; tokPos[t*2+1] = p1;
        tokGate[t*2]   = e0 * inv;
        tokGate[t*2+1] = e1 * inv;
    }
}

// ---------------- QKV GEMM (64x64 tile, depth-2) + fused attn prep epilogue ----------------
__global__ __launch_bounds__(256) void mm_qkv(const unsigned short* __restrict__ Ab,
                                              const unsigned short* __restrict__ Bb,
                                              const float* __restrict__ bias,
                                              unsigned short* __restrict__ Qb,
                                              unsigned short* __restrict__ Kb,
                                              unsigned short* __restrict__ Vt){
    __shared__ __align__(16) unsigned short As[2][64*32];
    __shared__ __align__(16) unsigned short Bs[2][64*32];
    int bm = blockIdx.y * 64, bn = blockIdx.x * 64;
    int tid = threadIdx.x, wave = tid >> 6, lane = tid & 63;
    int quad = lane >> 4, l15 = lane & 15;
    int wm = wave >> 1, wn = wave & 1;
    int arow = tid >> 2, achunk = (tid & 3) * 8;
    const unsigned short* aS = Ab + (size_t)(bm + arow) * DM + achunk;
    const unsigned short* bS = Bb + (size_t)(bn + arow) * DM + achunk;
    v4f acc[2][2];
    #pragma unroll
    for (int i = 0; i < 2; i++)
        #pragma unroll
        for (int j = 0; j < 2; j++) acc[i][j] = (v4f){0.f,0.f,0.f,0.f};

#define QKV_STAGE(buf, kt) do { int kb = (kt)*32; \
    GLDS16(aS + kb, &As[buf][(wave*16)*32]); \
    GLDS16(bS + kb, &Bs[buf][(wave*16)*32]); \
} while(0)
#define QKV_COMP(buf) do { \
    v8s a[2], bfr[2]; \
    _Pragma("unroll") \
    for (int i = 0; i < 2; i++){ \
        a[i]   = *(const v8s*)&As[buf][(wm*32 + i*16 + l15)*32 + quad*8]; \
        bfr[i] = *(const v8s*)&Bs[buf][(wn*32 + i*16 + l15)*32 + quad*8]; \
    } \
    _Pragma("unroll") \
    for (int mi = 0; mi < 2; mi++) \
        _Pragma("unroll") \
        for (int ni = 0; ni < 2; ni++) \
            acc[mi][ni] = __builtin_amdgcn_mfma_f32_16x16x32_bf16(a[mi], bfr[ni], acc[mi][ni], 0, 0, 0); \
} while(0)

    const int NK = DM/32;   // 24
    QKV_STAGE(0, 0);
    #pragma unroll 1
    for (int kt = 0; kt < NK; kt++){
        if (NK - kt > 1){ QKV_STAGE((kt+1)&1, kt+1); WAITV(2); }
        else            { WAITV(0); }
        BARF();
        QKV_COMP(kt&1);
        BARF();
    }
    int btyp = bn / DM;   // 0=Q, 1=K, 2=V (64 | 768)
    #pragma unroll
    for (int ni = 0; ni < 2; ni++){
        int n = bn + wn*32 + ni*16 + l15;
        float bb = bias[n];
        int hd = n % DM; int h = hd >> 6; int d = hd & 63;
        #pragma unroll
        for (int mi = 0; mi < 2; mi++){
            int m = bm + wm*32 + mi*16 + quad*4;
            int b = m >> 10, sd = m & 1023;
            size_t bhbase = (size_t)(b*NHEAD + h);
            if (btyp == 0){
                #pragma unroll
                for (int r = 0; r < 4; r++)
                    Qb[(bhbase*SEQ + sd + r)*HDIM + d] = f2bf((acc[mi][ni][r] + bb) * 0.125f);
            } else if (btyp == 1){
                #pragma unroll
                for (int r = 0; r < 4; r++)
                    Kb[(bhbase*SEQ + sd + r)*HDIM + d] = f2bf(acc[mi][ni][r] + bb);
            } else {
                ushort4 o;
                o.x = f2bf(acc[mi][ni][0] + bb); o.y = f2bf(acc[mi][ni][1] + bb);
                o.z = f2bf(acc[mi][ni][2] + bb); o.w = f2bf(acc[mi][ni][3] + bb);
                *(ushort4*)&Vt[(bhbase*HDIM + d)*SEQ + sd] = o;
            }
        }
    }
}

// ---------------- Flash attention: 2-wave K-split per (bh, 32-query tile) ----------------
__global__ __launch_bounds__(128) void fattn(const unsigned short* __restrict__ Qb,
                                             const unsigned short* __restrict__ Kb,
                                             const unsigned short* __restrict__ Vt,
                                             unsigned short* __restrict__ ctxb){
    int bh = blockIdx.x >> 5;
    int q0 = (31 - (blockIdx.x & 31)) * 32;   // long tiles first
    int h = bh % NHEAD, b = bh / NHEAD;
    int wv = threadIdx.x >> 6;                // wave 0 / 1
    int lane = threadIdx.x & 63;
    int quad = lane >> 4, l15 = lane & 15;

    __shared__ __align__(16) unsigned short Plds[2][32*32];
    __shared__ __align__(16) v4f Oex[2][4][64];
    __shared__ float Mm[2][4][64];
    __shared__ float Lm[2][4][64];

    const unsigned short* qp = Qb + ((size_t)bh*SEQ + q0 + l15) * HDIM + quad*8;
    v8s qa00 = *(const v8s*)qp;
    v8s qa01 = *(const v8s*)(qp + 32);
    v8s qa10 = *(const v8s*)(qp + 16*HDIM);
    v8s qa11 = *(const v8s*)(qp + 16*HDIM + 32);

    v4f o[2][4];
    #pragma unroll
    for (int i = 0; i < 2; i++)
        #pragma unroll
        for (int j = 0; j < 4; j++) o[i][j] = (v4f){0.f,0.f,0.f,0.f};
    float mrow[2][4], lrow[2][4];
    #pragma unroll
    for (int i = 0; i < 2; i++)
        #pragma unroll
        for (int r = 0; r < 4; r++){ mrow[i][r] = -1e30f; lrow[i][r] = 0.f; }

    int nch = (q0 >> 5) + 1;
    int halfc = (nch + 1) >> 1;
    int ch0 = wv ? halfc : 0;
    int ch1 = wv ? nch : halfc;
    unsigned short* Pw = &Plds[wv][0];

    // per-wave flash loop: no cross-wave LDS -> no barriers inside
    for (int ch = ch0; ch < ch1; ch++){
        int kt = ch * 32;
        const unsigned short* kp = Kb + ((size_t)bh*SEQ + kt + l15) * HDIM + quad*8;
        v8s k00 = *(const v8s*)kp;
        v8s k01 = *(const v8s*)(kp + 32);
        v8s k10 = *(const v8s*)(kp + 16*HDIM);
        v8s k11 = *(const v8s*)(kp + 16*HDIM + 32);
        v4f s00 = {0,0,0,0}, s01 = {0,0,0,0}, s10 = {0,0,0,0}, s11 = {0,0,0,0};
        s00 = __builtin_amdgcn_mfma_f32_16x16x32_bf16(qa00, k00, s00, 0, 0, 0);
        s00 = __builtin_amdgcn_mfma_f32_16x16x32_bf16(qa01, k01, s00, 0, 0, 0);
        s01 = __builtin_amdgcn_mfma_f32_16x16x32_bf16(qa00, k10, s01, 0, 0, 0);
        s01 = __builtin_amdgcn_mfma_f32_16x16x32_bf16(qa01, k11, s01, 0, 0, 0);
        s10 = __builtin_amdgcn_mfma_f32_16x16x32_bf16(qa10, k00, s10, 0, 0, 0);
        s10 = __builtin_amdgcn_mfma_f32_16x16x32_bf16(qa11, k01, s10, 0, 0, 0);
        s11 = __builtin_amdgcn_mfma_f32_16x16x32_bf16(qa10, k10, s11, 0, 0, 0);
        s11 = __builtin_amdgcn_mfma_f32_16x16x32_bf16(qa11, k11, s11, 0, 0, 0);

        int key0 = kt + l15, key1 = kt + 16 + l15;
        float alpha[2][4];
        #pragma unroll
        for (int mi = 0; mi < 2; mi++){
            #pragma unroll
            for (int r = 0; r < 4; r++){
                int qrow = q0 + mi*16 + quad*4 + r;
                float sv0 = mi ? s10[r] : s00[r];
                float sv1 = mi ? s11[r] : s01[r];
                float v0 = (key0 <= qrow) ? sv0 : -1e30f;
                float v1 = (key1 <= qrow) ? sv1 : -1e30f;
                float mx = fmaxf(v0, v1);
                mx = fmaxf(mx, __shfl_xor(mx, 1));
                mx = fmaxf(mx, __shfl_xor(mx, 2));
                mx = fmaxf(mx, __shfl_xor(mx, 4));
                mx = fmaxf(mx, __shfl_xor(mx, 8));
                float mn = fmaxf(mrow[mi][r], mx);
                alpha[mi][r] = __expf(mrow[mi][r] - mn);
                float p0 = __expf(v0 - mn);
                float p1 = __expf(v1 - mn);
                float ps = p0 + p1;
                ps += __shfl_xor(ps, 1);
                ps += __shfl_xor(ps, 2);
                ps += __shfl_xor(ps, 4);
                ps += __shfl_xor(ps, 8);
                lrow[mi][r] = lrow[mi][r] * alpha[mi][r] + ps;
                mrow[mi][r] = mn;
                Pw[(mi*16 + quad*4 + r)*32 + l15]      = f2bf(p0);
                Pw[(mi*16 + quad*4 + r)*32 + 16 + l15] = f2bf(p1);
            }
        }
        #pragma unroll
        for (int mi = 0; mi < 2; mi++)
            #pragma unroll
            for (int df = 0; df < 4; df++)
                #pragma unroll
                for (int r = 0; r < 4; r++)
                    o[mi][df][r] *= alpha[mi][r];
        v8s pa0 = *(const v8s*)&Pw[l15*32 + quad*8];
        v8s pa1 = *(const v8s*)&Pw[(16 + l15)*32 + quad*8];
        const unsigned short* vp = Vt + ((size_t)bh*HDIM + l15) * SEQ + kt + quad*8;
        #pragma unroll
        for (int df = 0; df < 4; df++){
            v8s vb = *(const v8s*)(vp + df*16*SEQ);
            o[0][df] = __builtin_amdgcn_mfma_f32_16x16x32_bf16(pa0, vb, o[0][df], 0, 0, 0);
            o[1][df] = __builtin_amdgcn_mfma_f32_16x16x32_bf16(pa1, vb, o[1][df], 0, 0, 0);
        }
    }

    // exchange: wave wv publishes its partial for rows mi = 1-wv (the half the other wave finalizes)
    int other = 1 - wv;
    #pragma unroll
    for (int df = 0; df < 4; df++) Oex[wv][df][lane] = o[other][df];
    #pragma unroll
    for (int r = 0; r < 4; r++){ Mm[wv][r][lane] = mrow[other][r]; Lm[wv][r][lane] = lrow[other][r]; }
    __syncthreads();
    v4f oth[4];
    #pragma unroll
    for (int df = 0; df < 4; df++) oth[df] = Oex[other][df][lane];   // other wave's o[wv]
    #pragma unroll
    for (int r = 0; r < 4; r++){
        float mo = Mm[other][r][lane], lo_ = Lm[other][r][lane];
        float mm = mrow[wv][r], lm = lrow[wv][r];
        float M = fmaxf(mm, mo);
        float am = __expf(mm - M), ao = __expf(mo - M);
        float L = lm*am + lo_*ao;
        float inv = 1.0f / L;
        size_t orow = (size_t)(b*SEQ + q0 + wv*16 + quad*4 + r) * DM + h*HDIM;
        #pragma unroll
        for (int df = 0; df < 4; df++)
            ctxb[orow + df*16 + l15] = f2bf((o[wv][df][r]*am + oth[df][r]*ao) * inv);
    }
}

// ---------------- attn-proj GEMM (64x64 tile, depth-3 prefetch) + bias + residual -> hs fp32 ----------------
__global__ __launch_bounds__(256) void mm_attnproj(const unsigned short* __restrict__ Ab,
                                                   const unsigned short* __restrict__ Bb,
                                                   const float* __restrict__ bias,
                                                   const float* __restrict__ res,
                                                   float* __restrict__ C){
    __shared__ __align__(16) unsigned short As[4][64*32];
    __shared__ __align__(16) unsigned short Bs[4][64*32];
    int bm = blockIdx.y * 64, bn = blockIdx.x * 64;
    int tid = threadIdx.x, wave = tid >> 6, lane = tid & 63;
    int quad = lane >> 4, l15 = lane & 15;
    int wm = wave >> 1, wn = wave & 1;
    int lrow = lane >> 2, lchunk = (lane & 3) * 8;
    const unsigned short* aS = Ab + (size_t)(bm + wave*16 + lrow) * DM + lchunk;
    const unsigned short* bS = Bb + (size_t)(bn + wave*16 + lrow) * DM + lchunk;
    v4f acc[2][2];
    #pragma unroll
    for (int i = 0; i < 2; i++)
        #pragma unroll
        for (int j = 0; j < 2; j++) acc[i][j] = (v4f){0.f,0.f,0.f,0.f};

#define AP_STAGE(buf, kt) do { int kb = (kt)*32; \
    GLDS16(aS + kb, &As[buf][(wave*16)*32]); \
    GLDS16(bS + kb, &Bs[buf][(wave*16)*32]); \
} while(0)
#define AP_COMP(buf) do { \
    v8s a[2], bfr[2]; \
    _Pragma("unroll") \
    for (int i = 0; i < 2; i++){ \
        a[i]   = *(const v8s*)&As[buf][(wm*32 + i*16 + l15)*32 + quad*8]; \
        bfr[i] = *(const v8s*)&Bs[buf][(wn*32 + i*16 + l15)*32 + quad*8]; \
    } \
    _Pragma("unroll") \
    for (int mi = 0; mi < 2; mi++) \
        _Pragma("unroll") \
        for (int ni = 0; ni < 2; ni++) \
            acc[mi][ni] = __builtin_amdgcn_mfma_f32_16x16x32_bf16(a[mi], bfr[ni], acc[mi][ni], 0, 0, 0); \
} while(0)

    const int NK = DM/32;   // 24
    AP_STAGE(0, 0); AP_STAGE(1, 1); AP_STAGE(2, 2);
    #pragma unroll 1
    for (int kt = 0; kt < NK; kt++){
        int rem = NK - kt;
        if (rem > 3){ AP_STAGE((kt+3)&3, kt+3); WAITV(6); }
        else if (rem == 3){ WAITV(4); }
        else if (rem == 2){ WAITV(2); }
        else { WAITV(0); }
        BARF();
        AP_COMP(kt&3);
        BARF();
    }
    #pragma unroll
    for (int ni = 0; ni < 2; ni++){
        int n = bn + wn*32 + ni*16 + l15;
        float bb = bias[n];
        #pragma unroll
        for (int mi = 0; mi < 2; mi++){
            int m = bm + wm*32 + mi*16 + quad*4;
            #pragma unroll
            for (int r = 0; r < 4; r++)
                C[(size_t)(m + r) * DM + n] = acc[mi][ni][r] + bb + res[(size_t)(m + r) * DM + n];
        }
    }
}

// ---------------- MoE fc (64x128 tile, depth-2, expert->XCD pinned, LDS-swizzled) ----------------
// grid: 1D, bid = e + 8*(tile + 32*bn_i)
__global__ __launch_bounds__(256) void mm_fc(const unsigned short* __restrict__ Xb,
                                             const unsigned short* __restrict__ Wb,
                                             const float* __restrict__ bfc,
                                             const int* __restrict__ expTok,
                                             const int* __restrict__ cnt,
                                             unsigned short* __restrict__ H){
    int bid = blockIdx.x;
    int e = bid & 7;
    int t2 = bid >> 3;
    int tile = t2 & 31;
    int bn = (t2 >> 5) * 128;
    int offe = 0, c = 0;
    #pragma unroll
    for (int j = 0; j < NEXP; j++){ int cj = cnt[j]; offe += (j < e) ? cj : 0; c = (j == e) ? cj : c; }
    int rows = c - tile * 64;
    if (rows <= 0) return;
    __shared__ __align__(16) unsigned short As[2][64*32];
    __shared__ __align__(16) unsigned short Bs[2][128*32];
    __shared__ int toks[64];
    int tid = threadIdx.x, wave = tid >> 6, lane = tid & 63;
    if (tid < 64){
        int idx = tile * 64 + tid;
        if (idx >= c) idx = c - 1;
        toks[tid] = expTok[e * NTOK + idx];
    }
    __syncthreads();
    int quad = lane >> 4, l15 = lane & 15;
    int wm = wave >> 1, wn = wave & 1;
    int lrow = lane >> 2;
    int pch = (((lane >> 3) & 3) ^ (lane & 3)) * 8;
    int tok0 = toks[wave*16 + lrow];
    const unsigned short* Be = Wb + (size_t)e * FF * DM;
    const unsigned short* aS  = Xb + (size_t)tok0 * DM + pch;
    const unsigned short* bS0 = Be + (size_t)(bn +      wave*16 + lrow) * DM + pch;
    const unsigned short* bS1 = Be + (size_t)(bn + 64 + wave*16 + lrow) * DM + pch;
    int q2 = (quad ^ ((l15 >> 1) & 3)) * 8;
    v4f acc[2][4];
    #pragma unroll
    for (int i = 0; i < 2; i++)
        #pragma unroll
        for (int j = 0; j < 4; j++) acc[i][j] = (v4f){0.f,0.f,0.f,0.f};

#define FC_STAGE(buf, kt) do { int kb = (kt)*32; \
    GLDS16(aS  + kb, &As[buf][(wave*16)*32]); \
    GLDS16(bS0 + kb, &Bs[buf][(     wave*16)*32]); \
    GLDS16(bS1 + kb, &Bs[buf][(64 + wave*16)*32]); \
} while(0)
#define FC_COMP(buf) do { \
    v8s a[2], bfr[4]; \
    _Pragma("unroll") \
    for (int i = 0; i < 2; i++) a[i] = *(const v8s*)&As[buf][(wm*32 + i*16 + l15)*32 + q2]; \
    _Pragma("unroll") \
    for (int i = 0; i < 4; i++) bfr[i] = *(const v8s*)&Bs[buf][(wn*64 + i*16 + l15)*32 + q2]; \
    _Pragma("unroll") \
    for (int mi = 0; mi < 2; mi++) \
        _Pragma("unroll") \
        for (int ni = 0; ni < 4; ni++) \
            acc[mi][ni] = __builtin_amdgcn_mfma_f32_16x16x32_bf16(a[mi], bfr[ni], acc[mi][ni], 0, 0, 0); \
} while(0)

    const int NK = DM/32;   // 24
    FC_STAGE(0, 0);
    #pragma unroll 1
    for (int kt = 0; kt < NK; kt++){
        if (NK - kt > 1){ FC_STAGE((kt+1)&1, kt+1); WAITV(3); }
        else            { WAITV(0); }
        BARF();
        FC_COMP(kt&1);
        BARF();
    }
    int slot0 = offe + tile * 64;
    #pragma unroll
    for (int ni = 0; ni < 4; ni++){
        int n = bn + wn*64 + ni*16 + l15;
        float bb = bfc[(size_t)e * FF + n];
        #pragma unroll
        for (int mi = 0; mi < 2; mi++){
            int ml = wm*32 + mi*16 + quad*4;
            #pragma unroll
            for (int r = 0; r < 4; r++)
                if (ml + r < rows)
                    H[(size_t)(slot0 + ml + r) * FF + n] = f2bf(gelu_exact(acc[mi][ni][r] + bb));
        }
    }
}

// ---------------- MoE proj (64x64 tile, split-K=2, depth-2, expert->XCD pinned, LDS-swizzled) ----------------
// grid: 1D, bid = e + 8*(tile + 32*(sk + 2*bn_i))
__global__ __launch_bounds__(256) void mm_proj(const unsigned short* __restrict__ H,
                                               const unsigned short* __restrict__ Wb,
                                               const int* __restrict__ cnt,
                                               float* __restrict__ Yp){
    int bid = blockIdx.x;
    int e = bid & 7;
    int t2 = bid >> 3;
    int tile = t2 & 31;
    int xx = t2 >> 5;
    int sk = xx & 1;
    int bn = (xx >> 1) * 64;
    int offe = 0, c = 0;
    #pragma unroll
    for (int j = 0; j < NEXP; j++){ int cj = cnt[j]; offe += (j < e) ? cj : 0; c = (j == e) ? cj : c; }
    int rows = c - tile * 64;
    if (rows <= 0) return;
    __shared__ __align__(16) unsigned short As[2][64*32];
    __shared__ __align__(16) unsigned short Bs[2][64*32];
    int tid = threadIdx.x, wave = tid >> 6, lane = tid & 63;
    int quad = lane >> 4, l15 = lane & 15;
    int wm = wave >> 1, wn = wave & 1;
    int slot0 = offe + tile * 64;
    int arow = tid >> 2;
    int pch = (((lane >> 3) & 3) ^ (lane & 3)) * 8;
    int arl = arow < rows ? arow : rows - 1;
    const unsigned short* Be = Wb + (size_t)e * DM * FF;
    const unsigned short* aS = H  + (size_t)(slot0 + arl) * FF + sk*1536 + pch;
    const unsigned short* bS = Be + (size_t)(bn + arow) * FF + sk*1536 + pch;
    int q2 = (quad ^ ((l15 >> 1) & 3)) * 8;
    v4f acc[2][2];
    #pragma unroll
    for (int i = 0; i < 2; i++)
        #pragma unroll
        for (int j = 0; j < 2; j++) acc[i][j] = (v4f){0.f,0.f,0.f,0.f};

#define PJ_STAGE(buf, kt) do { int kb = (kt)*32; \
    GLDS16(aS + kb, &As[buf][(wave*16)*32]); \
    GLDS16(bS + kb, &Bs[buf][(wave*16)*32]); \
} while(0)
#define PJ_COMP(buf) do { \
    v8s a[2], bfr[2]; \
    _Pragma("unroll") \
    for (int i = 0; i < 2; i++){ \
        a[i]   = *(const v8s*)&As[buf][(wm*32 + i*16 + l15)*32 + q2]; \
        bfr[i] = *(const v8s*)&Bs[buf][(wn*32 + i*16 + l15)*32 + q2]; \
    } \
    _Pragma("unroll") \
    for (int mi = 0; mi < 2; mi++) \
        _Pragma("unroll") \
        for (int ni = 0; ni < 2; ni++) \
            acc[mi][ni] = __builtin_amdgcn_mfma_f32_16x16x32_bf16(a[mi], bfr[ni], acc[mi][ni], 0, 0, 0); \
} while(0)

    const int NK = 1536/32;   // 48
    PJ_STAGE(0, 0);
    #pragma unroll 1
    for (int kt = 0; kt < NK; kt++){
        if (NK - kt > 1){ PJ_STAGE((kt+1)&1, kt+1); WAITV(2); }
        else            { WAITV(0); }
        BARF();
        PJ_COMP(kt&1);
        BARF();
    }
    float* Yo = Yp + (size_t)sk * NSLOT * DM;
    #pragma unroll
    for (int ni = 0; ni < 2; ni++){
        int n = bn + wn*32 + ni*16 + l15;
        #pragma unroll
        for (int mi = 0; mi < 2; mi++){
            int ml = wm*32 + mi*16 + quad*4;
            #pragma unroll
            for (int r = 0; r < 4; r++)
                if (ml + r < rows)
                    Yo[(size_t)(slot0 + ml + r) * DM + n] = acc[mi][ni][r];
        }
    }
}

// ---------------- Combine: out = hs + sum_k gate_k * (Yp0+Yp1 + b_proj[e_k]) ----------------
__global__ __launch_bounds__(256) void combine_kernel(const float* __restrict__ hs,
                                                      const float* __restrict__ Yp,
                                                      const float* __restrict__ bproj,
                                                      const int* __restrict__ tokE,
                                                      const int* __restrict__ tokPos,
                                                      const float* __restrict__ tokGate,
                                                      const int* __restrict__ cnt,
                                                      float* __restrict__ out){
    int t = blockIdx.x;
    int e0 = tokE[t*2], e1 = tokE[t*2+1];
    int off0 = 0, off1 = 0;
    #pragma unroll
    for (int j = 0; j < NEXP; j++){
        int cj = cnt[j];
        off0 += (j < e0) ? cj : 0;
        off1 += (j < e1) ? cj : 0;
    }
    int s0 = off0 + tokPos[t*2];
    int s1 = off1 + tokPos[t*2+1];
    float g0 = tokGate[t*2], g1 = tokGate[t*2+1];
    const float* y0a = Yp + (size_t)s0 * DM;
    const float* y0b = Yp + (size_t)NSLOT * DM + (size_t)s0 * DM;
    const float* y1a = Yp + (size_t)s1 * DM;
    const float* y1b = Yp + (size_t)NSLOT * DM + (size_t)s1 * DM;
    const float* b0 = bproj + (size_t)e0 * DM;
    const float* b1 = bproj + (size_t)e1 * DM;
    const float* hr = hs + (size_t)t * DM;
    float* orow = out + (size_t)t * DM;
    for (int d = threadIdx.x; d < DM; d += 256){
        orow[d] = hr[d] + g0 * (y0a[d] + y0b[d] + b0[d]) + g1 * (y1a[d] + y1b[d] + b1[d]);
    }
}

extern "C" void kernel_launch(void* const* d_in, const int* in_sizes, int n_in,
                              void* d_out, int out_size, void* d_ws, size_t ws_size,
                              hipStream_t stream){
    (void)in_sizes; (void)n_in; (void)out_size; (void)ws_size;
    const float* hidden  = (const float*)d_in[0];
    const float* ln1_g   = (const float*)d_in[1];
    const float* ln1_b   = (const float*)d_in[2];
    const float* w_attn  = (const float*)d_in[3];
    const float* b_attn  = (const float*)d_in[4];
    const float* w_aproj = (const float*)d_in[5];
    const float* b_aproj = (const float*)d_in[6];
    const float* ln2_g   = (const float*)d_in[7];
    const float* ln2_b   = (const float*)d_in[8];
    const float* w_rout  = (const float*)d_in[9];
    const float* w_fc    = (const float*)d_in[10];
    const float* b_fc    = (const float*)d_in[11];
    const float* w_proj  = (const float*)d_in[12];
    const float* b_proj  = (const float*)d_in[13];
    float* out = (float*)d_out;

    char* ws = (char*)d_ws;
    // layout (bytes):
    float*          hs   = (float*)(ws + 0);                      //  6,291,456
    unsigned short* xb   = (unsigned short*)(ws + 6291456);       //  3,145,728
    unsigned short* Qb   = (unsigned short*)(ws + 9437184);       //  3,145,728
    unsigned short* Kb   = (unsigned short*)(ws + 12582912);      //  3,145,728
    unsigned short* Vt   = (unsigned short*)(ws + 15728640);      //  3,145,728
    unsigned short* ctxb = (unsigned short*)(ws + 18874368);      //  3,145,728
    unsigned short* Wab  = (unsigned short*)(ws + 22020096);      //  3,538,944
    unsigned short* Wapb = (unsigned short*)(ws + 25559040);      //  1,179,648
    // H overlays Qb..Wapb (all dead by mm_fc) + fresh space up to 34,603,008
    unsigned short* H    = (unsigned short*)(ws + 9437184);       // 25,165,824 overlay
    unsigned short* Wfcb = (unsigned short*)(ws + 34603008);      // 37,748,736
    unsigned short* Wprb = (unsigned short*)(ws + 72351744);      // 37,748,736
    // Yp (2 split-K partials) overlays Wfcb (dead after mm_fc)
    float*          Yp   = (float*)(ws + 34603008);               // 25,165,824 overlay
    char* rt = ws + 110100480;
    int* cnt      = (int*)(rt + 0);
    int* expTok   = (int*)(rt + 128);                   // 65,536
    int* tokE     = (int*)(rt + 128 + 65536);           // 16,384
    int* tokPos   = (int*)(rt + 128 + 81920);           // 16,384
    float* tokGate= (float*)(rt + 128 + 98304);         // 16,384

    hipMemsetAsync(cnt, 0, NEXP * sizeof(int), stream);

    // weight transpose+convert to bf16 [N][K]  (v2: 64x32 tiles, 16B stores)
    tconv_kernel<<<dim3(TDIM/32, DM/64, 1), 256, 0, stream>>>(w_attn, Wab, DM, TDIM);
    tconv_kernel<<<dim3(DM/32, DM/64, 1), 256, 0, stream>>>(w_aproj, Wapb, DM, DM);
    tconv_kernel<<<dim3(FF/32, DM/64, NEXP), 256, 0, stream>>>(w_fc, Wfcb, DM, FF);
    tconv_kernel<<<dim3(DM/32, FF/64, NEXP), 256, 0, stream>>>(w_proj, Wprb, FF, DM);

    ln_b<<<NTOK, 256, 0, stream>>>(hidden, ln1_g, ln1_b, xb);
    mm_qkv<<<dim3(TDIM/64, NTOK/64), 256, 0, stream>>>(xb, Wab, b_attn, Qb, Kb, Vt);
    fattn<<<NB*NHEAD*32, 128, 0, stream>>>(Qb, Kb, Vt, ctxb);
    mm_attnproj<<<dim3(DM/64, NTOK/64), 256, 0, stream>>>(ctxb, Wapb, b_aproj, hidden, hs);
    ln_router<<<NTOK, 256, 0, stream>>>(hs, ln2_g, ln2_b, w_rout, xb,
                                        cnt, expTok, tokE, tokPos, tokGate);
    // 1D grids, expert in low 3 bits -> XCD pinning; offsets computed inline from cnt
    mm_fc<<<8 * (NTOK/64) * (FF/128), 256, 0, stream>>>(xb, Wfcb, b_fc, expTok, cnt, H);
    mm_proj<<<8 * (NTOK/64) * ((DM/64)*2), 256, 0, stream>>>(H, Wprb, cnt, Yp);
    combine_kernel<<<NTOK, 256, 0, stream>>>(hs, Yp, b_proj, tokE, tokPos, tokGate, cnt, out);
}